// Round 14
// baseline (292.155 us; speedup 1.0000x reference)
//
#include <hip/hip_runtime.h>
#include <hip/hip_bf16.h>
#include <hip/hip_cooperative_groups.h>
#include <math.h>
#include <stdint.h>

#define BB 4
#define SS 2048
#define DD 768
#define MM (BB*SS)       // 8192
#define MGRID 512

typedef __attribute__((ext_vector_type(4))) float  f32x4;
typedef __attribute__((ext_vector_type(8))) __bf16 bf16x8;
typedef __attribute__((ext_vector_type(4))) __bf16 bf16x4;

#define AS1 __attribute__((address_space(1)))
#define AS3 __attribute__((address_space(3)))

namespace cg = cooperative_groups;

// ======================================================================
// Cooperative mega-kernel (one dispatch). 512 blocks x 256 thr, 2 blk/CU.
// P0: LN(16 rows/blk, all) || G-gemm(0..143) || uvcb(144..336) || gather(480..511)
// P1: rgemm 128x96 (exactly 512 tiles) + atomic band-dot epilogue
// P2: scan (blocks 0..3)   P3: out, grid-strided x16
// ======================================================================
__global__ __launch_bounds__(256, 2) void mega_kernel(
        const float* __restrict__ x, const float* __restrict__ lw,
        const float* __restrict__ lb, const float* __restrict__ wq,
        const float* __restrict__ bq, const float* __restrict__ wk,
        const float* __restrict__ bk, const int* __restrict__ att,
        const float* __restrict__ prior,
        __bf16* __restrict__ G, float* __restrict__ u, float* __restrict__ v,
        float* __restrict__ cbp, __bf16* __restrict__ h, int* __restrict__ fl,
        float* __restrict__ prsup, float* __restrict__ du_g,
        float* __restrict__ dn_g, float* __restrict__ w_g,
        float* __restrict__ nbuf, double* __restrict__ P2,
        float* __restrict__ gout, float* __restrict__ nout) {
    __shared__ __attribute__((aligned(16))) union {
        struct { __bf16 As[128 * 32]; __bf16 Bs[96 * 32]; } g;              // 14 KB (P1)
        struct { __bf16 As[64][32]; __bf16 Bs[64][32]; } g0;                //  8 KB (P0)
        struct { float du[SS], dn[SS], w[SS], pd[SS]; double warr[256]; } s; // 34 KB (P2)
    } sm;
    cg::grid_group grid = cg::this_grid();
    const int bid = blockIdx.x;
    const int t = threadIdx.x;
    const int wave = t >> 6, lane = t & 63;

    // ================= P0 =================
    {
#pragma unroll
        for (int rr = 0; rr < 4; rr++) {               // LN: 16 rows/block
            const int row = bid * 16 + wave * 4 + rr;
            const float* xr = x + (size_t)row * DD + lane * 12;
            f32x4 a0 = *(const f32x4*)(xr), a1 = *(const f32x4*)(xr + 4), a2 = *(const f32x4*)(xr + 8);
            float xs[12];
#pragma unroll
            for (int c = 0; c < 4; c++) { xs[c] = a0[c]; xs[4 + c] = a1[c]; xs[8 + c] = a2[c]; }
            float s = 0.f, ss = 0.f;
#pragma unroll
            for (int c = 0; c < 12; c++) { s += xs[c]; ss += xs[c] * xs[c]; }
#pragma unroll
            for (int o = 1; o < 64; o <<= 1) { s += __shfl_xor(s, o); ss += __shfl_xor(ss, o); }
            const float mu = s * (1.0f / DD);
            const float var = ss * (1.0f / DD) - mu * mu;
            const float rstd = 1.0f / sqrtf(var + 1e-12f);
            const float* wp = lw + lane * 12; const float* bp = lb + lane * 12;
            f32x4 w0 = *(const f32x4*)(wp), w1 = *(const f32x4*)(wp + 4), w2 = *(const f32x4*)(wp + 8);
            f32x4 b0 = *(const f32x4*)(bp), b1 = *(const f32x4*)(bp + 4), b2 = *(const f32x4*)(bp + 8);
            bf16x4 o0, o1, o2;
#pragma unroll
            for (int c = 0; c < 4; c++) {
                o0[c] = (__bf16)((xs[c]     - mu) * rstd * w0[c] + b0[c]);
                o1[c] = (__bf16)((xs[4 + c] - mu) * rstd * w1[c] + b1[c]);
                o2[c] = (__bf16)((xs[8 + c] - mu) * rstd * w2[c] + b2[c]);
            }
            __bf16* hr = h + (size_t)row * DD + lane * 12;
            *(bf16x4*)(hr) = o0; *(bf16x4*)(hr + 4) = o1; *(bf16x4*)(hr + 8) = o2;
        }
        if (bid < 144) {
            // ---- G-gemm 64x64 ----
            const int m0 = (bid % 12) * 64;
            const int n0 = (bid / 12) * 64;
            const int wr = wave >> 1, wc = wave & 1;
            const int srow = t >> 2, scol = (t & 3) * 8;
            f32x4 acc[2][2] = {};
            for (int k0 = 0; k0 < DD; k0 += 32) {
                const float* ga = wq + (size_t)(m0 + srow) * DD + k0 + scol;
                const float* gb = wk + (size_t)(n0 + srow) * DD + k0 + scol;
                f32x4 a0 = *(const f32x4*)(ga), a1 = *(const f32x4*)(ga + 4);
                f32x4 b0 = *(const f32x4*)(gb), b1 = *(const f32x4*)(gb + 4);
                bf16x8 av, bv;
#pragma unroll
                for (int c = 0; c < 4; c++) {
                    av[c] = (__bf16)a0[c]; av[4 + c] = (__bf16)a1[c];
                    bv[c] = (__bf16)b0[c]; bv[4 + c] = (__bf16)b1[c];
                }
                __syncthreads();
                *(bf16x8*)&sm.g0.As[srow][scol] = av;
                *(bf16x8*)&sm.g0.Bs[srow][scol] = bv;
                __syncthreads();
                const int r = lane & 15, ko = (lane >> 4) << 3;
                bf16x8 af[2], bvf[2];
#pragma unroll
                for (int i = 0; i < 2; i++) af[i]  = *(const bf16x8*)&sm.g0.As[wr * 32 + i * 16 + r][ko];
#pragma unroll
                for (int j = 0; j < 2; j++) bvf[j] = *(const bf16x8*)&sm.g0.Bs[wc * 32 + j * 16 + r][ko];
#pragma unroll
                for (int i = 0; i < 2; i++)
#pragma unroll
                    for (int j = 0; j < 2; j++)
                        acc[i][j] = __builtin_amdgcn_mfma_f32_16x16x32_bf16(af[i], bvf[j], acc[i][j], 0, 0, 0);
            }
#pragma unroll
            for (int i = 0; i < 2; i++) {
                const int mm = m0 + wr * 32 + i * 16 + (lane >> 4) * 4;
#pragma unroll
                for (int j = 0; j < 2; j++) {
                    const int nn = n0 + wc * 32 + j * 16 + (lane & 15);
#pragma unroll
                    for (int rr = 0; rr < 4; rr++)
                        G[(size_t)(mm + rr) * DD + nn] = (__bf16)acc[i][j][rr];
                }
            }
        } else if (bid < 337) {
            // ---- uvcb: 2 ids per block ----
            const int base = (bid - 144) * 2;
#pragma unroll 1
            for (int q = 0; q < 2; q++) {
                const int id = base + q;
                if (id > 384) break;
                if (id == 384) {
                    if (wave == 0) {
                        float s = 0.f;
#pragma unroll
                        for (int m = 0; m < 12; m++) s += bq[lane + 64 * m] * bk[lane + 64 * m];
#pragma unroll
                        for (int o = 1; o < 64; o <<= 1) s += __shfl_xor(s, o);
                        if (lane == 0) cbp[0] = s;
                    }
                } else {
                    const bool isU = id < 192;
                    const int row = (isU ? id : id - 192) * 4 + wave;
                    const float* W = isU ? wq : wk;
                    const float* bvec = isU ? bk : bq;
                    const float* wr_ = W + (size_t)row * DD;
                    float s = 0.f;
#pragma unroll
                    for (int m = 0; m < 12; m++) s += wr_[lane + 64 * m] * bvec[lane + 64 * m];
#pragma unroll
                    for (int o = 1; o < 64; o <<= 1) s += __shfl_xor(s, o);
                    if (lane == 0) (isU ? u : v)[row] = s;
                }
            }
        } else if (bid >= 480) {
            // ---- gather + zero accumulators ----
            const int idx = (bid - 480) * 256 + t;      // 0..8191
            const int b = idx >> 11, s = idx & 2047;
            const bool au = (s < SS - 1) && ((att[((size_t)b * SS + s) * SS + (s + 1)] & 1) != 0);
            const bool ad = (s > 0)      && ((att[((size_t)b * SS + s) * SS + (s - 1)] & 1) != 0);
            fl[idx] = (au ? 1 : 0) | (ad ? 2 : 0);
            if (s < SS - 1)
                prsup[idx] = prior[((size_t)b * SS + s) * SS + s + 1];
            du_g[idx] = 0.f; dn_g[idx] = 0.f; w_g[idx] = 0.f;
        }
    }
    grid.sync();
    // ================= P1: rgemm 128x96 + atomic band-dot epilogue =================
    {
        const int mt = bid & 63, nt = bid >> 6;        // 64 x 8 tiles
        const int m0 = mt * 128, n0 = nt * 96;
        const int wr = wave >> 1, wc = wave & 1;
        f32x4 acc[4][3] = {};
        char* asb = (char*)sm.g.As;
        char* bsb = (char*)sm.g.Bs;
        const int rgrp = lane >> 2;                    // 0..15
        const int slot = lane & 3;
#pragma unroll 1
        for (int k0 = 0; k0 < DD; k0 += 32) {
#pragma unroll
            for (int i2 = 0; i2 < 2; i2++) {
                const int j = wave * 2 + i2;           // 0..7
                const int R = j * 16 + rgrp;
                const int csw = (slot ^ ((R >> 1) & 3)) << 3;
                __builtin_amdgcn_global_load_lds((const AS1 void*)(h + (size_t)(m0 + R) * DD + k0 + csw),
                                                 (AS3 void*)(asb + j * 1024), 16, 0, 0);
                if (j < 6)
                    __builtin_amdgcn_global_load_lds((const AS1 void*)(G + (size_t)(n0 + R) * DD + k0 + csw),
                                                     (AS3 void*)(bsb + j * 1024), 16, 0, 0);
            }
            __syncthreads();
            const int r = lane & 15, ks = lane >> 4;
            bf16x8 af[4], bvf[3];
#pragma unroll
            for (int i = 0; i < 4; i++) {
                const int R = wr * 64 + i * 16 + r;
                af[i] = *(const bf16x8*)&sm.g.As[R * 32 + ((ks ^ ((R >> 1) & 3)) << 3)];
            }
#pragma unroll
            for (int j = 0; j < 3; j++) {
                const int R = wc * 48 + j * 16 + r;
                bvf[j] = *(const bf16x8*)&sm.g.Bs[R * 32 + ((ks ^ ((R >> 1) & 3)) << 3)];
            }
#pragma unroll
            for (int i = 0; i < 4; i++)
#pragma unroll
                for (int j = 0; j < 3; j++)
                    acc[i][j] = __builtin_amdgcn_mfma_f32_16x16x32_bf16(af[i], bvf[j], acc[i][j], 0, 0, 0);
            __syncthreads();
        }
        int colg[3]; float ub[3], vb2[3];
#pragma unroll
        for (int j = 0; j < 3; j++) {
            colg[j] = n0 + wc * 48 + j * 16 + (lane & 15);
            ub[j] = u[colg[j]];
            vb2[j] = v[colg[j]];
        }
#pragma unroll
        for (int i = 0; i < 4; i++) {
#pragma unroll
            for (int rr = 0; rr < 4; rr++) {
                const int row = m0 + wr * 64 + i * 16 + (lane >> 4) * 4 + rr;
                const int rm = (row == 0) ? 0 : row - 1;
                const int rp = (row == MM - 1) ? MM - 1 : row + 1;
                const __bf16* hm = h + (size_t)rm * DD;
                const __bf16* hz = h + (size_t)row * DD;
                const __bf16* hp = h + (size_t)rp * DD;
                float dua = 0.f, dna = 0.f, wa = 0.f;
#pragma unroll
                for (int j = 0; j < 3; j++) {
                    const float Rv = acc[i][j][rr] + ub[j];
                    dua += Rv * (float)hm[colg[j]];
                    dna += Rv * (float)hp[colg[j]];
                    wa  += vb2[j] * (float)hz[colg[j]];
                }
#pragma unroll
                for (int o = 1; o < 16; o <<= 1) {
                    dua += __shfl_xor(dua, o);
                    dna += __shfl_xor(dna, o);
                    wa  += __shfl_xor(wa, o);
                }
                if ((lane & 15) == 0) {
                    atomicAdd(&du_g[row], dua);
                    atomicAdd(&dn_g[row], dna);
                    atomicAdd(&w_g[row], wa);
                }
            }
        }
    }
    grid.sync();
    // ================= P2: scan (blocks 0..3) =================
    if (bid < BB) {
        const int b = bid;
        for (int xx = t; xx < SS; xx += 256) {
            sm.s.du[xx] = du_g[b * SS + xx];
            sm.s.dn[xx] = dn_g[b * SS + xx];
            sm.s.w[xx]  = w_g[b * SS + xx];
        }
        __syncthreads();
        const float cb = cbp[0];
        float pu_r[8];
#pragma unroll
        for (int e = 0; e < 8; e++) {
            const int s = t * 8 + e;
            const int flg = fl[b * SS + s];
            const bool au = flg & 1, ad = flg & 2;
            float puv = 0.f, pdv = 0.f;
            if (au || ad) {
                const float eu = au ? (sm.s.du[s + 1] + sm.s.w[s + 1] + cb) * (1.0f / DD) : 0.f;
                const float ed = ad ? (sm.s.dn[s - 1] + sm.s.w[s - 1] + cb) * (1.0f / DD) : 0.f;
                float mx = au ? eu : ed;
                if (au && ad) mx = fmaxf(eu, ed);
                const float zu = au ? expf(eu - mx) : 0.f;
                const float zd = ad ? expf(ed - mx) : 0.f;
                const float iz = 1.f / (zu + zd);
                puv = zu * iz; pdv = zd * iz;
            }
            pu_r[e] = puv;
            sm.s.pd[s] = pdv;
        }
        __syncthreads();
        double L[8];
        double mysum = 0.0;
#pragma unroll
        for (int e = 0; e < 8; e++) {
            const int s = t * 8 + e;
            double Lv = 0.0;
            float nbv = 0.f;
            if (s < SS - 1) {
                nbv = sqrtf(pu_r[e] * sm.s.pd[s + 1] + 1e-9f);
                const float pr = prsup[b * SS + s];
                const float nsup = pr + (1.f - pr) * nbv;
                Lv = (double)log2f(nsup + 1e-9f);
            }
            nbuf[b * SS + s] = nbv;
            L[e] = Lv; mysum += Lv;
        }
        sm.s.warr[t] = mysum;
        __syncthreads();
        for (int o = 1; o < 256; o <<= 1) {
            double vv = 0.0;
            if (t >= o) vv = sm.s.warr[t - o];
            __syncthreads();
            if (t >= o) sm.s.warr[t] += vv;
            __syncthreads();
        }
        double run = sm.s.warr[t] - mysum;
#pragma unroll
        for (int e = 0; e < 8; e++) {
            P2[(size_t)b * SS + t * 8 + e] = run;
            run += L[e];
        }
    }
    grid.sync();
    // ================= P3: output, grid-strided =================
#pragma unroll 1
    for (int vb = bid; vb < 8192; vb += MGRID) {
        const size_t t8 = (size_t)vb * 256 + t;
        const int b = (int)(t8 >> 19);
        const size_t off = t8 << 3;
        const size_t rr_ = off & ((1u << 22) - 1);
        const int i  = (int)(rr_ >> 11);
        const int k0 = (int)(rr_ & 2047);
        const f32x4 p0 = *(const f32x4*)(prior + off);
        const f32x4 p1 = *(const f32x4*)(prior + off + 4);
        const double* Pb = P2 + ((size_t)b << 11);
        const double Pi = Pb[i];
        const float* nbb = nbuf + ((size_t)b << 11);
        f32x4 g0, g1, n0v, n1v;
#pragma unroll
        for (int c = 0; c < 8; c++) {
            const int k = k0 + c;
            const float pr = (c < 4) ? p0[c] : p1[c - 4];
            float vv = 3.16227766016838e-5f;           // sqrt(1e-9)
            if (k == i + 1)      vv = nbb[i];
            else if (k == i - 1) vv = nbb[k];
            const float nval = pr + (1.f - pr) * vv;
            float g;
            if (k == i) {
                g = nval;
            } else {
                const double Pk = Pb[k];
                const double dd = (k > i) ? (Pk - Pi) : (Pi - Pk);
                g = exp2f((float)dd) + 1e-9f;
            }
            if (c < 4) { g0[c] = g; n0v[c] = nval; }
            else       { g1[c - 4] = g; n1v[c - 4] = nval; }
        }
        *(f32x4*)(gout + off)     = g0;
        *(f32x4*)(gout + off + 4) = g1;
        *(f32x4*)(nout + off)     = n0v;
        *(f32x4*)(nout + off + 4) = n1v;
    }
}

// ======================================================================
// Fallback chain — byte-identical to R13 champion (97.7 us)
// ======================================================================
__global__ __launch_bounds__(256) void combined_kernel(
        const float* __restrict__ x, const float* __restrict__ lw,
        const float* __restrict__ lb, const float* __restrict__ wq,
        const float* __restrict__ wk, const float* __restrict__ bq,
        const float* __restrict__ bk, const int* __restrict__ att,
        const float* __restrict__ prior, __bf16* __restrict__ G,
        float* __restrict__ u, float* __restrict__ v, float* __restrict__ cb,
        __bf16* __restrict__ h, int* __restrict__ fl, float* __restrict__ prsup,
        float* __restrict__ du_g, float* __restrict__ dn_g, float* __restrict__ w_g) {
    __shared__ __attribute__((aligned(16))) __bf16 As[64][32];
    __shared__ __attribute__((aligned(16))) __bf16 Bs[64][32];
    const int bid = blockIdx.x;
    if (bid >= 2577) {
        const int idx = (bid - 2577) * 256 + threadIdx.x;
        const int b = idx >> 11, s = idx & 2047;
        const bool au = (s < SS - 1) && ((att[((size_t)b * SS + s) * SS + (s + 1)] & 1) != 0);
        const bool ad = (s > 0)      && ((att[((size_t)b * SS + s) * SS + (s - 1)] & 1) != 0);
        fl[idx] = (au ? 1 : 0) | (ad ? 2 : 0);
        if (s < SS - 1)
            prsup[idx] = prior[((size_t)b * SS + s) * SS + s + 1];
        du_g[idx] = 0.f; dn_g[idx] = 0.f; w_g[idx] = 0.f;
        return;
    }
    if (bid >= 529) {
        const int row = (bid - 529) * 4 + (threadIdx.x >> 6);
        const int lane = threadIdx.x & 63;
        const float* xr = x + (size_t)row * DD + lane * 12;
        f32x4 a0 = *(const f32x4*)(xr), a1 = *(const f32x4*)(xr + 4), a2 = *(const f32x4*)(xr + 8);
        float xs[12];
#pragma unroll
        for (int c = 0; c < 4; c++) { xs[c] = a0[c]; xs[4 + c] = a1[c]; xs[8 + c] = a2[c]; }
        float s = 0.f, ss = 0.f;
#pragma unroll
        for (int c = 0; c < 12; c++) { s += xs[c]; ss += xs[c] * xs[c]; }
#pragma unroll
        for (int o = 1; o < 64; o <<= 1) { s += __shfl_xor(s, o); ss += __shfl_xor(ss, o); }
        const float mu = s * (1.0f / DD);
        const float var = ss * (1.0f / DD) - mu * mu;
        const float rstd = 1.0f / sqrtf(var + 1e-12f);
        const float* wp = lw + lane * 12; const float* bp = lb + lane * 12;
        f32x4 w0 = *(const f32x4*)(wp), w1 = *(const f32x4*)(wp + 4), w2 = *(const f32x4*)(wp + 8);
        f32x4 b0 = *(const f32x4*)(bp), b1 = *(const f32x4*)(bp + 4), b2 = *(const f32x4*)(bp + 8);
        bf16x4 o0, o1, o2;
#pragma unroll
        for (int c = 0; c < 4; c++) {
            o0[c] = (__bf16)((xs[c]     - mu) * rstd * w0[c] + b0[c]);
            o1[c] = (__bf16)((xs[4 + c] - mu) * rstd * w1[c] + b1[c]);
            o2[c] = (__bf16)((xs[8 + c] - mu) * rstd * w2[c] + b2[c]);
        }
        __bf16* hr = h + (size_t)row * DD + lane * 12;
        *(bf16x4*)(hr) = o0; *(bf16x4*)(hr + 4) = o1; *(bf16x4*)(hr + 8) = o2;
        return;
    }
    if (bid >= 144) {
        const int id = bid - 144;
        const int lane = threadIdx.x & 63, wv_ = threadIdx.x >> 6;
        if (id == 384) {
            if (wv_ != 0) return;
            float s = 0.f;
#pragma unroll
            for (int m = 0; m < 12; m++) s += bq[lane + 64 * m] * bk[lane + 64 * m];
#pragma unroll
            for (int o = 1; o < 64; o <<= 1) s += __shfl_xor(s, o);
            if (lane == 0) cb[0] = s;
            return;
        }
        const bool isU = id < 192;
        const int row = (isU ? id : id - 192) * 4 + wv_;
        const float* W = isU ? wq : wk;
        const float* bvec = isU ? bk : bq;
        const float* wr_ = W + (size_t)row * DD;
        float s = 0.f;
#pragma unroll
        for (int m = 0; m < 12; m++) s += wr_[lane + 64 * m] * bvec[lane + 64 * m];
#pragma unroll
        for (int o = 1; o < 64; o <<= 1) s += __shfl_xor(s, o);
        if (lane == 0) (isU ? u : v)[row] = s;
        return;
    }
    const int m0 = (bid % 12) * 64;
    const int n0 = (bid / 12) * 64;
    const int t = threadIdx.x;
    const int wave = t >> 6, lane = t & 63;
    const int wr = wave >> 1, wc = wave & 1;
    const int srow = t >> 2, scol = (t & 3) * 8;
    f32x4 acc[2][2] = {};

    for (int k0 = 0; k0 < DD; k0 += 32) {
        const float* ga = wq + (size_t)(m0 + srow) * DD + k0 + scol;
        const float* gb = wk + (size_t)(n0 + srow) * DD + k0 + scol;
        f32x4 a0 = *(const f32x4*)(ga), a1 = *(const f32x4*)(ga + 4);
        f32x4 b0 = *(const f32x4*)(gb), b1 = *(const f32x4*)(gb + 4);
        bf16x8 av, bv;
#pragma unroll
        for (int c = 0; c < 4; c++) {
            av[c] = (__bf16)a0[c]; av[4 + c] = (__bf16)a1[c];
            bv[c] = (__bf16)b0[c]; bv[4 + c] = (__bf16)b1[c];
        }
        __syncthreads();
        *(bf16x8*)&As[srow][scol] = av;
        *(bf16x8*)&Bs[srow][scol] = bv;
        __syncthreads();
        const int r = lane & 15, ko = (lane >> 4) << 3;
        bf16x8 af[2], bvf[2];
#pragma unroll
        for (int i = 0; i < 2; i++) af[i]  = *(const bf16x8*)&As[wr * 32 + i * 16 + r][ko];
#pragma unroll
        for (int j = 0; j < 2; j++) bvf[j] = *(const bf16x8*)&Bs[wc * 32 + j * 16 + r][ko];
#pragma unroll
        for (int i = 0; i < 2; i++)
#pragma unroll
            for (int j = 0; j < 2; j++)
                acc[i][j] = __builtin_amdgcn_mfma_f32_16x16x32_bf16(af[i], bvf[j], acc[i][j], 0, 0, 0);
    }
#pragma unroll
    for (int i = 0; i < 2; i++) {
        const int mm = m0 + wr * 32 + i * 16 + (lane >> 4) * 4;
#pragma unroll
        for (int j = 0; j < 2; j++) {
            const int nn = n0 + wc * 32 + j * 16 + (lane & 15);
#pragma unroll
            for (int rr = 0; rr < 4; rr++)
                G[(size_t)(mm + rr) * DD + nn] = (__bf16)acc[i][j][rr];
        }
    }
}

__global__ __launch_bounds__(256) void rgemm_kernel(const __bf16* __restrict__ A,
        const __bf16* __restrict__ Bt, const float* __restrict__ u,
        const float* __restrict__ v, float* __restrict__ du_g,
        float* __restrict__ dn_g, float* __restrict__ w_g) {
    __shared__ __attribute__((aligned(16))) __bf16 As[64 * 32];
    __shared__ __attribute__((aligned(16))) __bf16 Bs[128 * 32];
    const int bid = blockIdx.x;
    const int mt = bid & 127, nt = bid >> 7;
    const int m0 = mt * 64, n0 = nt * 128;
    const int t = threadIdx.x;
    const int wave = t >> 6, lane = t & 63;
    const int wr = wave >> 1, wc = wave & 1;
    f32x4 acc[2][4] = {};

    char* asb = (char*)As;
    char* bsb = (char*)Bs;
    const int rloc = lane >> 2;
    const int slot = lane & 3;
    const int rA = wave * 16 + rloc;
    const int csw = (slot ^ ((rA >> 1) & 3)) << 3;

    for (int k0 = 0; k0 < DD; k0 += 32) {
        const __bf16* ga  = A  + (size_t)(m0 + rA) * DD + k0 + csw;
        const __bf16* gb0 = Bt + (size_t)(n0 + rA) * DD + k0 + csw;
        const __bf16* gb1 = gb0 + (size_t)64 * DD;
        __builtin_amdgcn_global_load_lds((const AS1 void*)(ga),  (AS3 void*)(asb + wave * 1024),        16, 0, 0);
        __builtin_amdgcn_global_load_lds((const AS1 void*)(gb0), (AS3 void*)(bsb + wave * 1024),        16, 0, 0);
        __builtin_amdgcn_global_load_lds((const AS1 void*)(gb1), (AS3 void*)(bsb + 4096 + wave * 1024), 16, 0, 0);
        __syncthreads();
        const int r = lane & 15, ks = lane >> 4;
        bf16x8 af[2], bvf[4];
#pragma unroll
        for (int i = 0; i < 2; i++) {
            const int R = wr * 32 + i * 16 + r;
            af[i] = *(const bf16x8*)&As[R * 32 + ((ks ^ ((R >> 1) & 3)) << 3)];
        }
#pragma unroll
        for (int j = 0; j < 4; j++) {
            const int R = wc * 64 + j * 16 + r;
            bvf[j] = *(const bf16x8*)&Bs[R * 32 + ((ks ^ ((R >> 1) & 3)) << 3)];
        }
#pragma unroll
        for (int i = 0; i < 2; i++)
#pragma unroll
            for (int j = 0; j < 4; j++)
                acc[i][j] = __builtin_amdgcn_mfma_f32_16x16x32_bf16(af[i], bvf[j], acc[i][j], 0, 0, 0);
        __syncthreads();
    }
    int colg[4]; float ub[4], vb[4];
#pragma unroll
    for (int j = 0; j < 4; j++) {
        colg[j] = n0 + wc * 64 + j * 16 + (lane & 15);
        ub[j] = u[colg[j]];
        vb[j] = v[colg[j]];
    }
#pragma unroll
    for (int i = 0; i < 2; i++) {
#pragma unroll
        for (int rr = 0; rr < 4; rr++) {
            const int row = m0 + wr * 32 + i * 16 + (lane >> 4) * 4 + rr;
            const int rm = (row == 0) ? 0 : row - 1;
            const int rp = (row == MM - 1) ? MM - 1 : row + 1;
            const __bf16* hm = A + (size_t)rm * DD;
            const __bf16* hz = A + (size_t)row * DD;
            const __bf16* hp = A + (size_t)rp * DD;
            float dua = 0.f, dna = 0.f, wa = 0.f;
#pragma unroll
            for (int j = 0; j < 4; j++) {
                const float Rv = acc[i][j][rr] + ub[j];
                dua += Rv * (float)hm[colg[j]];
                dna += Rv * (float)hp[colg[j]];
                wa  += vb[j] * (float)hz[colg[j]];
            }
#pragma unroll
            for (int o = 1; o < 16; o <<= 1) {
                dua += __shfl_xor(dua, o);
                dna += __shfl_xor(dna, o);
                wa  += __shfl_xor(wa, o);
            }
            if ((lane & 15) == 0) {
                atomicAdd(&du_g[row], dua);
                atomicAdd(&dn_g[row], dna);
                atomicAdd(&w_g[row], wa);
            }
        }
    }
}

__global__ __launch_bounds__(256) void scan_kernel(const float* __restrict__ du_g,
        const float* __restrict__ dn_g, const float* __restrict__ w_g,
        const float* __restrict__ cbp, const int* __restrict__ fl_i,
        const float* __restrict__ prsup,
        float* __restrict__ nb, double* __restrict__ P2) {
    const int b = blockIdx.x;
    const int t = threadIdx.x;
    __shared__ float du_s[SS], dn_s[SS], w_s[SS], sh_pd[SS];
    __shared__ double warr[256];
    for (int x = t; x < SS; x += 256) {
        du_s[x] = du_g[b * SS + x];
        dn_s[x] = dn_g[b * SS + x];
        w_s[x]  = w_g[b * SS + x];
    }
    __syncthreads();
    const float cb = cbp[0];
    float pu_r[8];
#pragma unroll
    for (int e = 0; e < 8; e++) {
        const int s = t * 8 + e;
        const int fl = fl_i[b * SS + s];
        const bool au = fl & 1, ad = fl & 2;
        float puv = 0.f, pdv = 0.f;
        if (au || ad) {
            const float eu = au ? (du_s[s + 1] + w_s[s + 1] + cb) * (1.0f / DD) : 0.f;
            const float ed = ad ? (dn_s[s - 1] + w_s[s - 1] + cb) * (1.0f / DD) : 0.f;
            float mx = au ? eu : ed;
            if (au && ad) mx = fmaxf(eu, ed);
            const float zu = au ? expf(eu - mx) : 0.f;
            const float zd = ad ? expf(ed - mx) : 0.f;
            const float iz = 1.f / (zu + zd);
            puv = zu * iz; pdv = zd * iz;
        }
        pu_r[e] = puv;
        sh_pd[s] = pdv;
    }
    __syncthreads();
    double L[8];
    double mysum = 0.0;
#pragma unroll
    for (int e = 0; e < 8; e++) {
        const int s = t * 8 + e;
        double Lv = 0.0;
        float nbv = 0.f;
        if (s < SS - 1) {
            nbv = sqrtf(pu_r[e] * sh_pd[s + 1] + 1e-9f);
            const float pr = prsup[b * SS + s];
            const float nsup = pr + (1.f - pr) * nbv;
            Lv = (double)log2f(nsup + 1e-9f);
        }
        nb[b * SS + s] = nbv;
        L[e] = Lv; mysum += Lv;
    }
    warr[t] = mysum;
    __syncthreads();
    for (int o = 1; o < 256; o <<= 1) {
        double vv = 0.0;
        if (t >= o) vv = warr[t - o];
        __syncthreads();
        if (t >= o) warr[t] += vv;
        __syncthreads();
    }
    double run = warr[t] - mysum;
#pragma unroll
    for (int e = 0; e < 8; e++) {
        P2[(size_t)b * SS + t * 8 + e] = run;
        run += L[e];
    }
}

__global__ __launch_bounds__(256) void out_kernel(const float* __restrict__ prior,
        const float* __restrict__ nb, const double* __restrict__ P2,
        float* __restrict__ gout, float* __restrict__ nout) {
    const size_t t8 = (size_t)blockIdx.x * 256 + threadIdx.x;
    const int b = (int)(t8 >> 19);
    const size_t off = t8 << 3;
    const size_t r = off & ((1u << 22) - 1);
    const int i  = (int)(r >> 11);
    const int k0 = (int)(r & 2047);
    const f32x4 p0 = *(const f32x4*)(prior + off);
    const f32x4 p1 = *(const f32x4*)(prior + off + 4);
    const double* Pb = P2 + ((size_t)b << 11);
    const double Pi = Pb[i];
    const float* nbb = nb + ((size_t)b << 11);
    f32x4 g0, g1, n0, n1;
#pragma unroll
    for (int c = 0; c < 8; c++) {
        const int k = k0 + c;
        const float pr = (c < 4) ? p0[c] : p1[c - 4];
        float vv = 3.16227766016838e-5f;
        if (k == i + 1)      vv = nbb[i];
        else if (k == i - 1) vv = nbb[k];
        const float nval = pr + (1.f - pr) * vv;
        float g;
        if (k == i) {
            g = nval;
        } else {
            const double Pk = Pb[k];
            const double dd = (k > i) ? (Pk - Pi) : (Pi - Pk);
            g = exp2f((float)dd) + 1e-9f;
        }
        if (c < 4) { g0[c] = g; n0[c] = nval; }
        else       { g1[c - 4] = g; n1[c - 4] = nval; }
    }
    *(f32x4*)(gout + off)     = g0;
    *(f32x4*)(gout + off + 4) = g1;
    *(f32x4*)(nout + off)     = n0;
    *(f32x4*)(nout + off + 4) = n1;
}

extern "C" void kernel_launch(void* const* d_in, const int* in_sizes, int n_in,
                              void* d_out, int out_size, void* d_ws, size_t ws_size,
                              hipStream_t stream) {
    const float* hs    = (const float*)d_in[0];
    const int*   att   = (const int*)d_in[1];
    const float* prior = (const float*)d_in[2];
    const float* ln_w  = (const float*)d_in[3];
    const float* ln_b  = (const float*)d_in[4];
    const float* wq    = (const float*)d_in[5];
    const float* bq    = (const float*)d_in[6];
    const float* wk    = (const float*)d_in[7];
    const float* bk    = (const float*)d_in[8];

    float* gout = (float*)d_out;                       // g first (return order)
    float* nout = gout + (size_t)BB * SS * SS;

    char* ws = (char*)d_ws;
    __bf16* h     = (__bf16*)(ws);                     // 12,582,912
    __bf16* G     = (__bf16*)(ws + 12582912);          //  1,179,648
    float*  u     = (float*) (ws + 13762560);          //      3,072
    float*  v     = (float*) (ws + 13765632);          //      3,072
    float*  cbp   = (float*) (ws + 13768704);          //        256
    int*    fl    = (int*)   (ws + 13768960);          //     32,768
    float*  prsup = (float*) (ws + 13801728);          //     32,768
    float*  du_g  = (float*) (ws + 13834496);          //     32,768
    float*  dn_g  = (float*) (ws + 13867264);          //     32,768
    float*  w_g   = (float*) (ws + 13900032);          //     32,768
    float*  nbuf  = (float*) (ws + 13932800);          //     32,768
    double* P2    = (double*)(ws + 13965568);          //     65,536

    // ---- decide coop path via pure host-side queries (graph-capture safe) ----
    bool useCoop = false;
    {
        int dev = 0;
        if (hipGetDevice(&dev) == hipSuccess) {
            int coop = 0, nCU = 0, maxBlk = 0;
            hipDeviceGetAttribute(&coop, hipDeviceAttributeCooperativeLaunch, dev);
            hipDeviceGetAttribute(&nCU, hipDeviceAttributeMultiprocessorCount, dev);
            hipError_t oe = hipOccupancyMaxActiveBlocksPerMultiprocessor(&maxBlk, mega_kernel, 256, 0);
            useCoop = (coop != 0) && (oe == hipSuccess) && ((long)maxBlk * nCU >= MGRID);
        }
    }
    if (useCoop) {
        void* args[] = {
            (void*)&hs, (void*)&ln_w, (void*)&ln_b, (void*)&wq, (void*)&bq,
            (void*)&wk, (void*)&bk, (void*)&att, (void*)&prior,
            (void*)&G, (void*)&u, (void*)&v, (void*)&cbp, (void*)&h, (void*)&fl,
            (void*)&prsup, (void*)&du_g, (void*)&dn_g, (void*)&w_g,
            (void*)&nbuf, (void*)&P2, (void*)&gout, (void*)&nout
        };
        if (hipLaunchCooperativeKernel((const void*)mega_kernel, dim3(MGRID), dim3(256),
                                       args, 0, stream) == hipSuccess)
            return;
        (void)hipGetLastError();   // clear and fall through to the 4-kernel chain
    }
    combined_kernel<<<dim3(2609), dim3(256), 0, stream>>>(hs, ln_w, ln_b, wq, wk, bq, bk,
                                                          att, prior, G, u, v, cbp, h, fl, prsup,
                                                          du_g, dn_g, w_g);
    rgemm_kernel<<<dim3(768), dim3(256), 0, stream>>>(h, G, u, v, du_g, dn_g, w_g);
    scan_kernel<<<dim3(BB), dim3(256), 0, stream>>>(du_g, dn_g, w_g, cbp, fl, prsup, nbuf, P2);
    out_kernel<<<dim3((BB * SS * SS / 8) / 256), dim3(256), 0, stream>>>(prior, nbuf, P2, gout, nout);
}

// Round 15
// 238.263 us; speedup vs baseline: 1.2262x; 1.2262x over previous
//
#include <hip/hip_runtime.h>
#include <hip/hip_bf16.h>
#include <math.h>
#include <stdint.h>

#define BB 4
#define SS 2048
#define DD 768
#define MM (BB*SS)       // 8192

typedef __attribute__((ext_vector_type(4))) float  f32x4;
typedef __attribute__((ext_vector_type(8))) __bf16 bf16x8;
typedef __attribute__((ext_vector_type(4))) __bf16 bf16x4;

#define AS1 __attribute__((address_space(1)))
#define AS3 __attribute__((address_space(3)))

// ============ K0: combined front kernel (identical to R13) ============
__global__ __launch_bounds__(256) void combined_kernel(
        const float* __restrict__ x, const float* __restrict__ lw,
        const float* __restrict__ lb, const float* __restrict__ wq,
        const float* __restrict__ wk, const float* __restrict__ bq,
        const float* __restrict__ bk, const int* __restrict__ att,
        const float* __restrict__ prior, __bf16* __restrict__ G,
        float* __restrict__ u, float* __restrict__ v, float* __restrict__ cb,
        __bf16* __restrict__ h, int* __restrict__ fl, float* __restrict__ prsup,
        float* __restrict__ du_g, float* __restrict__ dn_g, float* __restrict__ w_g) {
    __shared__ __attribute__((aligned(16))) __bf16 As[64][32];
    __shared__ __attribute__((aligned(16))) __bf16 Bs[64][32];
    const int bid = blockIdx.x;
    if (bid >= 2577) {
        // ---- gather + accumulator zeroing ----
        const int idx = (bid - 2577) * 256 + threadIdx.x;   // 0..8191
        const int b = idx >> 11, s = idx & 2047;
        const bool au = (s < SS - 1) && ((att[((size_t)b * SS + s) * SS + (s + 1)] & 1) != 0);
        const bool ad = (s > 0)      && ((att[((size_t)b * SS + s) * SS + (s - 1)] & 1) != 0);
        fl[idx] = (au ? 1 : 0) | (ad ? 2 : 0);
        if (s < SS - 1)
            prsup[idx] = prior[((size_t)b * SS + s) * SS + s + 1];
        du_g[idx] = 0.f; dn_g[idx] = 0.f; w_g[idx] = 0.f;
        return;
    }
    if (bid >= 529) {
        // ---- LayerNorm ----
        const int row = (bid - 529) * 4 + (threadIdx.x >> 6);
        const int lane = threadIdx.x & 63;
        const float* xr = x + (size_t)row * DD + lane * 12;
        f32x4 a0 = *(const f32x4*)(xr), a1 = *(const f32x4*)(xr + 4), a2 = *(const f32x4*)(xr + 8);
        float xs[12];
#pragma unroll
        for (int c = 0; c < 4; c++) { xs[c] = a0[c]; xs[4 + c] = a1[c]; xs[8 + c] = a2[c]; }
        float s = 0.f, ss = 0.f;
#pragma unroll
        for (int c = 0; c < 12; c++) { s += xs[c]; ss += xs[c] * xs[c]; }
#pragma unroll
        for (int o = 1; o < 64; o <<= 1) { s += __shfl_xor(s, o); ss += __shfl_xor(ss, o); }
        const float mu = s * (1.0f / DD);
        const float var = ss * (1.0f / DD) - mu * mu;
        const float rstd = 1.0f / sqrtf(var + 1e-12f);
        const float* wp = lw + lane * 12; const float* bp = lb + lane * 12;
        f32x4 w0 = *(const f32x4*)(wp), w1 = *(const f32x4*)(wp + 4), w2 = *(const f32x4*)(wp + 8);
        f32x4 b0 = *(const f32x4*)(bp), b1 = *(const f32x4*)(bp + 4), b2 = *(const f32x4*)(bp + 8);
        bf16x4 o0, o1, o2;
#pragma unroll
        for (int c = 0; c < 4; c++) {
            o0[c] = (__bf16)((xs[c]     - mu) * rstd * w0[c] + b0[c]);
            o1[c] = (__bf16)((xs[4 + c] - mu) * rstd * w1[c] + b1[c]);
            o2[c] = (__bf16)((xs[8 + c] - mu) * rstd * w2[c] + b2[c]);
        }
        __bf16* hr = h + (size_t)row * DD + lane * 12;
        *(bf16x4*)(hr) = o0; *(bf16x4*)(hr + 4) = o1; *(bf16x4*)(hr + 8) = o2;
        return;
    }
    if (bid >= 144) {
        // ---- uvcb ----
        const int id = bid - 144;
        const int lane = threadIdx.x & 63, wv_ = threadIdx.x >> 6;
        if (id == 384) {
            if (wv_ != 0) return;
            float s = 0.f;
#pragma unroll
            for (int m = 0; m < 12; m++) s += bq[lane + 64 * m] * bk[lane + 64 * m];
#pragma unroll
            for (int o = 1; o < 64; o <<= 1) s += __shfl_xor(s, o);
            if (lane == 0) cb[0] = s;
            return;
        }
        const bool isU = id < 192;
        const int row = (isU ? id : id - 192) * 4 + wv_;
        const float* W = isU ? wq : wk;
        const float* bvec = isU ? bk : bq;
        const float* wr_ = W + (size_t)row * DD;
        float s = 0.f;
#pragma unroll
        for (int m = 0; m < 12; m++) s += wr_[lane + 64 * m] * bvec[lane + 64 * m];
#pragma unroll
        for (int o = 1; o < 64; o <<= 1) s += __shfl_xor(s, o);
        if (lane == 0) (isU ? u : v)[row] = s;
        return;
    }
    // ---- G-gemm: G[d,e] = sum_j wq[d,j] * wk[e,j], 64x64 tile ----
    const int m0 = (bid % 12) * 64;
    const int n0 = (bid / 12) * 64;
    const int t = threadIdx.x;
    const int wave = t >> 6, lane = t & 63;
    const int wr = wave >> 1, wc = wave & 1;
    const int srow = t >> 2, scol = (t & 3) * 8;    // 4 threads/row, 8 fp32 each
    f32x4 acc[2][2] = {};

    for (int k0 = 0; k0 < DD; k0 += 32) {
        const float* ga = wq + (size_t)(m0 + srow) * DD + k0 + scol;
        const float* gb = wk + (size_t)(n0 + srow) * DD + k0 + scol;
        f32x4 a0 = *(const f32x4*)(ga), a1 = *(const f32x4*)(ga + 4);
        f32x4 b0 = *(const f32x4*)(gb), b1 = *(const f32x4*)(gb + 4);
        bf16x8 av, bv;
#pragma unroll
        for (int c = 0; c < 4; c++) {
            av[c] = (__bf16)a0[c]; av[4 + c] = (__bf16)a1[c];
            bv[c] = (__bf16)b0[c]; bv[4 + c] = (__bf16)b1[c];
        }
        __syncthreads();
        *(bf16x8*)&As[srow][scol] = av;
        *(bf16x8*)&Bs[srow][scol] = bv;
        __syncthreads();
        const int r = lane & 15, ko = (lane >> 4) << 3;
        bf16x8 af[2], bvf[2];
#pragma unroll
        for (int i = 0; i < 2; i++) af[i]  = *(const bf16x8*)&As[wr * 32 + i * 16 + r][ko];
#pragma unroll
        for (int j = 0; j < 2; j++) bvf[j] = *(const bf16x8*)&Bs[wc * 32 + j * 16 + r][ko];
#pragma unroll
        for (int i = 0; i < 2; i++)
#pragma unroll
            for (int j = 0; j < 2; j++)
                acc[i][j] = __builtin_amdgcn_mfma_f32_16x16x32_bf16(af[i], bvf[j], acc[i][j], 0, 0, 0);
    }
#pragma unroll
    for (int i = 0; i < 2; i++) {
        const int mm = m0 + wr * 32 + i * 16 + (lane >> 4) * 4;
#pragma unroll
        for (int j = 0; j < 2; j++) {
            const int nn = n0 + wc * 32 + j * 16 + (lane & 15);
#pragma unroll
            for (int rr = 0; rr < 4; rr++)
                G[(size_t)(mm + rr) * DD + nn] = (__bf16)acc[i][j][rr];
        }
    }
}

// ============ K1: fused R-gemm + band dots (identical to R13) ============
__global__ __launch_bounds__(256) void rgemm_kernel(const __bf16* __restrict__ A,
        const __bf16* __restrict__ Bt, const float* __restrict__ u,
        const float* __restrict__ v, float* __restrict__ du_g,
        float* __restrict__ dn_g, float* __restrict__ w_g) {
    __shared__ __attribute__((aligned(16))) __bf16 As[64 * 32];
    __shared__ __attribute__((aligned(16))) __bf16 Bs[128 * 32];
    const int bid = blockIdx.x;
    const int mt = bid & 127, nt = bid >> 7;
    const int m0 = mt * 64, n0 = nt * 128;
    const int t = threadIdx.x;
    const int wave = t >> 6, lane = t & 63;
    const int wr = wave >> 1, wc = wave & 1;
    f32x4 acc[2][4] = {};

    char* asb = (char*)As;
    char* bsb = (char*)Bs;
    const int rloc = lane >> 2;               // 0..15 row within wave-issue
    const int slot = lane & 3;                // 16B slot within 64B row
    const int rA = wave * 16 + rloc;          // tile-local row 0..63
    const int csw = (slot ^ ((rA >> 1) & 3)) << 3;   // swizzled element col

    for (int k0 = 0; k0 < DD; k0 += 32) {
        const __bf16* ga  = A  + (size_t)(m0 + rA) * DD + k0 + csw;
        const __bf16* gb0 = Bt + (size_t)(n0 + rA) * DD + k0 + csw;
        const __bf16* gb1 = gb0 + (size_t)64 * DD;
        __builtin_amdgcn_global_load_lds((const AS1 void*)(ga),  (AS3 void*)(asb + wave * 1024),        16, 0, 0);
        __builtin_amdgcn_global_load_lds((const AS1 void*)(gb0), (AS3 void*)(bsb + wave * 1024),        16, 0, 0);
        __builtin_amdgcn_global_load_lds((const AS1 void*)(gb1), (AS3 void*)(bsb + 4096 + wave * 1024), 16, 0, 0);
        __syncthreads();
        const int r = lane & 15, ks = lane >> 4;   // logical 16B slot 0..3
        bf16x8 af[2], bvf[4];
#pragma unroll
        for (int i = 0; i < 2; i++) {
            const int R = wr * 32 + i * 16 + r;
            af[i] = *(const bf16x8*)&As[R * 32 + ((ks ^ ((R >> 1) & 3)) << 3)];
        }
#pragma unroll
        for (int j = 0; j < 4; j++) {
            const int R = wc * 64 + j * 16 + r;
            bvf[j] = *(const bf16x8*)&Bs[R * 32 + ((ks ^ ((R >> 1) & 3)) << 3)];
        }
#pragma unroll
        for (int i = 0; i < 2; i++)
#pragma unroll
            for (int j = 0; j < 4; j++)
                acc[i][j] = __builtin_amdgcn_mfma_f32_16x16x32_bf16(af[i], bvf[j], acc[i][j], 0, 0, 0);
        __syncthreads();
    }
    // ---- fused epilogue: band dots, atomic global reduce ----
    int colg[4]; float ub[4], vb[4];
#pragma unroll
    for (int j = 0; j < 4; j++) {
        colg[j] = n0 + wc * 64 + j * 16 + (lane & 15);
        ub[j] = u[colg[j]];
        vb[j] = v[colg[j]];
    }
#pragma unroll
    for (int i = 0; i < 2; i++) {
#pragma unroll
        for (int rr = 0; rr < 4; rr++) {
            const int row = m0 + wr * 32 + i * 16 + (lane >> 4) * 4 + rr;
            const int rm = (row == 0) ? 0 : row - 1;
            const int rp = (row == MM - 1) ? MM - 1 : row + 1;
            const __bf16* hm = A + (size_t)rm * DD;
            const __bf16* hz = A + (size_t)row * DD;
            const __bf16* hp = A + (size_t)rp * DD;
            float dua = 0.f, dna = 0.f, wa = 0.f;
#pragma unroll
            for (int j = 0; j < 4; j++) {
                const float Rv = acc[i][j][rr] + ub[j];
                dua += Rv * (float)hm[colg[j]];
                dna += Rv * (float)hp[colg[j]];
                wa  += vb[j] * (float)hz[colg[j]];
            }
#pragma unroll
            for (int o = 1; o < 16; o <<= 1) {
                dua += __shfl_xor(dua, o);
                dna += __shfl_xor(dna, o);
                wa  += __shfl_xor(wa, o);
            }
            if ((lane & 15) == 0) {
                atomicAdd(&du_g[row], dua);
                atomicAdd(&dn_g[row], dna);
                atomicAdd(&w_g[row], wa);
            }
        }
    }
}

// ============ K2: fused in-block scan + output (one row per block) ============
// Each block owns row (b,i). It recomputes the per-batch softmax/log2/prefix
// (deterministic, identical in every block of batch b; same op order as the
// old scan_kernel) and then writes its 2048-element row of g and n.
// Thread t's locally computed prefix values ARE P2[k] for k = t*8..t*8+7.
__global__ __launch_bounds__(256) void out_kernel(const float* __restrict__ prior,
        const float* __restrict__ du_g, const float* __restrict__ dn_g,
        const float* __restrict__ w_g, const float* __restrict__ cbp,
        const int* __restrict__ fl_i, const float* __restrict__ prsup,
        float* __restrict__ gout, float* __restrict__ nout) {
    __shared__ float sh_pd[SS];        // 8 KB
    __shared__ double warr[256];       // 2 KB
    __shared__ double sh_P2i;
    __shared__ float sh_nbi, sh_nbim1;
    const int bid = blockIdx.x;        // 0..8191
    const int b = bid >> 11;
    const int i = bid & 2047;
    const int t = threadIdx.x;
    const float cb = cbp[0];

    // ---- phase 1: 2-way softmax for this thread's 8 rows ----
    float pu_r[8];
#pragma unroll
    for (int e = 0; e < 8; e++) {
        const int s = t * 8 + e;
        const int idx = b * SS + s;
        const int flg = fl_i[idx];
        const bool au = flg & 1, ad = flg & 2;
        float puv = 0.f, pdv = 0.f;
        if (au || ad) {
            float eu = 0.f, ed = 0.f;
            if (au) eu = (du_g[idx + 1] + w_g[idx + 1] + cb) * (1.0f / DD);
            if (ad) ed = (dn_g[idx - 1] + w_g[idx - 1] + cb) * (1.0f / DD);
            float mx = au ? eu : ed;
            if (au && ad) mx = fmaxf(eu, ed);
            const float zu = au ? expf(eu - mx) : 0.f;
            const float zd = ad ? expf(ed - mx) : 0.f;
            const float iz = 1.f / (zu + zd);
            puv = zu * iz; pdv = zd * iz;
        }
        pu_r[e] = puv;
        sh_pd[s] = pdv;
    }
    __syncthreads();
    // ---- phase 2: band n, log2, local sums ----
    double L[8];
    double mysum = 0.0;
#pragma unroll
    for (int e = 0; e < 8; e++) {
        const int s = t * 8 + e;
        double Lv = 0.0;
        float nbv = 0.f;
        if (s < SS - 1) {
            nbv = sqrtf(pu_r[e] * sh_pd[s + 1] + 1e-9f);
            const float pr = prsup[b * SS + s];
            const float nsup = pr + (1.f - pr) * nbv;
            Lv = (double)log2f(nsup + 1e-9f);
        }
        if (s == i)     sh_nbi   = nbv;
        if (s == i - 1) sh_nbim1 = nbv;
        L[e] = Lv; mysum += Lv;
    }
    warr[t] = mysum;
    __syncthreads();
    // ---- phase 3: block prefix over per-thread sums ----
    for (int o = 1; o < 256; o <<= 1) {
        double vv = 0.0;
        if (t >= o) vv = warr[t - o];
        __syncthreads();
        if (t >= o) warr[t] += vv;
        __syncthreads();
    }
    double run = warr[t] - mysum;      // exclusive prefix
    double P2loc[8];
#pragma unroll
    for (int e = 0; e < 8; e++) {
        P2loc[e] = run;
        if (t * 8 + e == i) sh_P2i = run;
        run += L[e];
    }
    __syncthreads();
    // ---- phase 4: write this row of g and n ----
    const double Pi = sh_P2i;
    const float nbi = sh_nbi, nbim1 = sh_nbim1;
    const size_t off = ((size_t)bid << 11) + (size_t)t * 8;
    const f32x4 p0 = *(const f32x4*)(prior + off);
    const f32x4 p1 = *(const f32x4*)(prior + off + 4);
    f32x4 g0, g1, n0, n1;
#pragma unroll
    for (int c = 0; c < 8; c++) {
        const int k = t * 8 + c;
        const float pr = (c < 4) ? p0[c] : p1[c - 4];
        float vv = 3.16227766016838e-5f;   // sqrt(1e-9)
        if (k == i + 1)      vv = nbi;
        else if (k == i - 1) vv = nbim1;
        const float nval = pr + (1.f - pr) * vv;
        float g;
        if (k == i) {
            g = nval;
        } else {
            const double dd = (k > i) ? (P2loc[c] - Pi) : (Pi - P2loc[c]);
            g = exp2f((float)dd) + 1e-9f;
        }
        if (c < 4) { g0[c] = g; n0[c] = nval; }
        else       { g1[c - 4] = g; n1[c - 4] = nval; }
    }
    *(f32x4*)(gout + off)     = g0;
    *(f32x4*)(gout + off + 4) = g1;
    *(f32x4*)(nout + off)     = n0;
    *(f32x4*)(nout + off + 4) = n1;
}

extern "C" void kernel_launch(void* const* d_in, const int* in_sizes, int n_in,
                              void* d_out, int out_size, void* d_ws, size_t ws_size,
                              hipStream_t stream) {
    const float* hs    = (const float*)d_in[0];
    const int*   att   = (const int*)d_in[1];
    const float* prior = (const float*)d_in[2];
    const float* ln_w  = (const float*)d_in[3];
    const float* ln_b  = (const float*)d_in[4];
    const float* wq    = (const float*)d_in[5];
    const float* bq    = (const float*)d_in[6];
    const float* wk    = (const float*)d_in[7];
    const float* bk    = (const float*)d_in[8];

    float* gout = (float*)d_out;                       // g first (return order)
    float* nout = gout + (size_t)BB * SS * SS;

    char* ws = (char*)d_ws;
    __bf16* h     = (__bf16*)(ws);                     // 12,582,912
    __bf16* G     = (__bf16*)(ws + 12582912);          //  1,179,648
    float*  u     = (float*) (ws + 13762560);          //      3,072
    float*  v     = (float*) (ws + 13765632);          //      3,072
    float*  cbp   = (float*) (ws + 13768704);          //        256
    int*    fl    = (int*)   (ws + 13768960);          //     32,768
    float*  prsup = (float*) (ws + 13801728);          //     32,768
    float*  du_g  = (float*) (ws + 13834496);          //     32,768
    float*  dn_g  = (float*) (ws + 13867264);          //     32,768
    float*  w_g   = (float*) (ws + 13900032);          //     32,768

    combined_kernel<<<dim3(2609), dim3(256), 0, stream>>>(hs, ln_w, ln_b, wq, wk, bq, bk,
                                                          att, prior, G, u, v, cbp, h, fl, prsup,
                                                          du_g, dn_g, w_g);
    rgemm_kernel<<<dim3(768), dim3(256), 0, stream>>>(h, G, u, v, du_g, dn_g, w_g);
    out_kernel<<<dim3(MM), dim3(256), 0, stream>>>(prior, du_g, dn_g, w_g, cbp, fl, prsup, gout, nout);
}

// Round 16
// 97.025 us; speedup vs baseline: 3.0111x; 2.4557x over previous
//
#include <hip/hip_runtime.h>
#include <hip/hip_bf16.h>
#include <math.h>
#include <stdint.h>

#define BB 4
#define SS 2048
#define DD 768
#define MM (BB*SS)       // 8192

typedef __attribute__((ext_vector_type(4))) float  f32x4;
typedef __attribute__((ext_vector_type(8))) __bf16 bf16x8;
typedef __attribute__((ext_vector_type(4))) __bf16 bf16x4;

#define AS1 __attribute__((address_space(1)))
#define AS3 __attribute__((address_space(3)))

// ============ K0: combined front kernel ============
// blocks [0,144):     G = Wq @ Wk^T, 64x64 tiles (12x12), fp32 reg-staged
// blocks [144,529):   u = Wq@bk (192), v = Wk@bq (192), cb = bq.bk (1)
// blocks [529,2577):  LayerNorm, 4 rows/block (wave per row)
// blocks [2577,2609): att-flag + prior-superdiag gather + zero du/dn/w accumulators
__global__ __launch_bounds__(256) void combined_kernel(
        const float* __restrict__ x, const float* __restrict__ lw,
        const float* __restrict__ lb, const float* __restrict__ wq,
        const float* __restrict__ wk, const float* __restrict__ bq,
        const float* __restrict__ bk, const int* __restrict__ att,
        const float* __restrict__ prior, __bf16* __restrict__ G,
        float* __restrict__ u, float* __restrict__ v, float* __restrict__ cb,
        __bf16* __restrict__ h, int* __restrict__ fl, float* __restrict__ prsup,
        float* __restrict__ du_g, float* __restrict__ dn_g, float* __restrict__ w_g) {
    __shared__ __attribute__((aligned(16))) __bf16 As[64][32];
    __shared__ __attribute__((aligned(16))) __bf16 Bs[64][32];
    const int bid = blockIdx.x;
    if (bid >= 2577) {
        // ---- gather + accumulator zeroing ----
        const int idx = (bid - 2577) * 256 + threadIdx.x;   // 0..8191
        const int b = idx >> 11, s = idx & 2047;
        const bool au = (s < SS - 1) && ((att[((size_t)b * SS + s) * SS + (s + 1)] & 1) != 0);
        const bool ad = (s > 0)      && ((att[((size_t)b * SS + s) * SS + (s - 1)] & 1) != 0);
        fl[idx] = (au ? 1 : 0) | (ad ? 2 : 0);
        if (s < SS - 1)
            prsup[idx] = prior[((size_t)b * SS + s) * SS + s + 1];
        du_g[idx] = 0.f; dn_g[idx] = 0.f; w_g[idx] = 0.f;
        return;
    }
    if (bid >= 529) {
        // ---- LayerNorm ----
        const int row = (bid - 529) * 4 + (threadIdx.x >> 6);
        const int lane = threadIdx.x & 63;
        const float* xr = x + (size_t)row * DD + lane * 12;
        f32x4 a0 = *(const f32x4*)(xr), a1 = *(const f32x4*)(xr + 4), a2 = *(const f32x4*)(xr + 8);
        float xs[12];
#pragma unroll
        for (int c = 0; c < 4; c++) { xs[c] = a0[c]; xs[4 + c] = a1[c]; xs[8 + c] = a2[c]; }
        float s = 0.f, ss = 0.f;
#pragma unroll
        for (int c = 0; c < 12; c++) { s += xs[c]; ss += xs[c] * xs[c]; }
#pragma unroll
        for (int o = 1; o < 64; o <<= 1) { s += __shfl_xor(s, o); ss += __shfl_xor(ss, o); }
        const float mu = s * (1.0f / DD);
        const float var = ss * (1.0f / DD) - mu * mu;
        const float rstd = 1.0f / sqrtf(var + 1e-12f);
        const float* wp = lw + lane * 12; const float* bp = lb + lane * 12;
        f32x4 w0 = *(const f32x4*)(wp), w1 = *(const f32x4*)(wp + 4), w2 = *(const f32x4*)(wp + 8);
        f32x4 b0 = *(const f32x4*)(bp), b1 = *(const f32x4*)(bp + 4), b2 = *(const f32x4*)(bp + 8);
        bf16x4 o0, o1, o2;
#pragma unroll
        for (int c = 0; c < 4; c++) {
            o0[c] = (__bf16)((xs[c]     - mu) * rstd * w0[c] + b0[c]);
            o1[c] = (__bf16)((xs[4 + c] - mu) * rstd * w1[c] + b1[c]);
            o2[c] = (__bf16)((xs[8 + c] - mu) * rstd * w2[c] + b2[c]);
        }
        __bf16* hr = h + (size_t)row * DD + lane * 12;
        *(bf16x4*)(hr) = o0; *(bf16x4*)(hr + 4) = o1; *(bf16x4*)(hr + 8) = o2;
        return;
    }
    if (bid >= 144) {
        // ---- uvcb ----
        const int id = bid - 144;
        const int lane = threadIdx.x & 63, wv_ = threadIdx.x >> 6;
        if (id == 384) {
            if (wv_ != 0) return;
            float s = 0.f;
#pragma unroll
            for (int m = 0; m < 12; m++) s += bq[lane + 64 * m] * bk[lane + 64 * m];
#pragma unroll
            for (int o = 1; o < 64; o <<= 1) s += __shfl_xor(s, o);
            if (lane == 0) cb[0] = s;
            return;
        }
        const bool isU = id < 192;
        const int row = (isU ? id : id - 192) * 4 + wv_;
        const float* W = isU ? wq : wk;
        const float* bvec = isU ? bk : bq;
        const float* wr_ = W + (size_t)row * DD;
        float s = 0.f;
#pragma unroll
        for (int m = 0; m < 12; m++) s += wr_[lane + 64 * m] * bvec[lane + 64 * m];
#pragma unroll
        for (int o = 1; o < 64; o <<= 1) s += __shfl_xor(s, o);
        if (lane == 0) (isU ? u : v)[row] = s;
        return;
    }
    // ---- G-gemm: G[d,e] = sum_j wq[d,j] * wk[e,j], 64x64 tile ----
    const int m0 = (bid % 12) * 64;
    const int n0 = (bid / 12) * 64;
    const int t = threadIdx.x;
    const int wave = t >> 6, lane = t & 63;
    const int wr = wave >> 1, wc = wave & 1;
    const int srow = t >> 2, scol = (t & 3) * 8;    // 4 threads/row, 8 fp32 each
    f32x4 acc[2][2] = {};

    for (int k0 = 0; k0 < DD; k0 += 32) {
        const float* ga = wq + (size_t)(m0 + srow) * DD + k0 + scol;
        const float* gb = wk + (size_t)(n0 + srow) * DD + k0 + scol;
        f32x4 a0 = *(const f32x4*)(ga), a1 = *(const f32x4*)(ga + 4);
        f32x4 b0 = *(const f32x4*)(gb), b1 = *(const f32x4*)(gb + 4);
        bf16x8 av, bv;
#pragma unroll
        for (int c = 0; c < 4; c++) {
            av[c] = (__bf16)a0[c]; av[4 + c] = (__bf16)a1[c];
            bv[c] = (__bf16)b0[c]; bv[4 + c] = (__bf16)b1[c];
        }
        __syncthreads();
        *(bf16x8*)&As[srow][scol] = av;
        *(bf16x8*)&Bs[srow][scol] = bv;
        __syncthreads();
        const int r = lane & 15, ko = (lane >> 4) << 3;
        bf16x8 af[2], bvf[2];
#pragma unroll
        for (int i = 0; i < 2; i++) af[i]  = *(const bf16x8*)&As[wr * 32 + i * 16 + r][ko];
#pragma unroll
        for (int j = 0; j < 2; j++) bvf[j] = *(const bf16x8*)&Bs[wc * 32 + j * 16 + r][ko];
#pragma unroll
        for (int i = 0; i < 2; i++)
#pragma unroll
            for (int j = 0; j < 2; j++)
                acc[i][j] = __builtin_amdgcn_mfma_f32_16x16x32_bf16(af[i], bvf[j], acc[i][j], 0, 0, 0);
    }
#pragma unroll
    for (int i = 0; i < 2; i++) {
        const int mm = m0 + wr * 32 + i * 16 + (lane >> 4) * 4;
#pragma unroll
        for (int j = 0; j < 2; j++) {
            const int nn = n0 + wc * 32 + j * 16 + (lane & 15);
#pragma unroll
            for (int rr = 0; rr < 4; rr++)
                G[(size_t)(mm + rr) * DD + nn] = (__bf16)acc[i][j][rr];
        }
    }
}

// ============ K1: fused R-gemm + band dots (BK=32, slot-swizzled LDS, atomic reduce) ============
__global__ __launch_bounds__(256) void rgemm_kernel(const __bf16* __restrict__ A,
        const __bf16* __restrict__ Bt, const float* __restrict__ u,
        const float* __restrict__ v, float* __restrict__ du_g,
        float* __restrict__ dn_g, float* __restrict__ w_g) {
    __shared__ __attribute__((aligned(16))) __bf16 As[64 * 32];
    __shared__ __attribute__((aligned(16))) __bf16 Bs[128 * 32];
    const int bid = blockIdx.x;
    const int mt = bid & 127, nt = bid >> 7;
    const int m0 = mt * 64, n0 = nt * 128;
    const int t = threadIdx.x;
    const int wave = t >> 6, lane = t & 63;
    const int wr = wave >> 1, wc = wave & 1;
    f32x4 acc[2][4] = {};

    char* asb = (char*)As;
    char* bsb = (char*)Bs;
    const int rloc = lane >> 2;               // 0..15 row within wave-issue
    const int slot = lane & 3;                // 16B slot within 64B row
    const int rA = wave * 16 + rloc;          // tile-local row 0..63
    const int csw = (slot ^ ((rA >> 1) & 3)) << 3;   // swizzled element col

    for (int k0 = 0; k0 < DD; k0 += 32) {
        const __bf16* ga  = A  + (size_t)(m0 + rA) * DD + k0 + csw;
        const __bf16* gb0 = Bt + (size_t)(n0 + rA) * DD + k0 + csw;
        const __bf16* gb1 = gb0 + (size_t)64 * DD;
        __builtin_amdgcn_global_load_lds((const AS1 void*)(ga),  (AS3 void*)(asb + wave * 1024),        16, 0, 0);
        __builtin_amdgcn_global_load_lds((const AS1 void*)(gb0), (AS3 void*)(bsb + wave * 1024),        16, 0, 0);
        __builtin_amdgcn_global_load_lds((const AS1 void*)(gb1), (AS3 void*)(bsb + 4096 + wave * 1024), 16, 0, 0);
        __syncthreads();
        const int r = lane & 15, ks = lane >> 4;   // logical 16B slot 0..3
        bf16x8 af[2], bvf[4];
#pragma unroll
        for (int i = 0; i < 2; i++) {
            const int R = wr * 32 + i * 16 + r;
            af[i] = *(const bf16x8*)&As[R * 32 + ((ks ^ ((R >> 1) & 3)) << 3)];
        }
#pragma unroll
        for (int j = 0; j < 4; j++) {
            const int R = wc * 64 + j * 16 + r;
            bvf[j] = *(const bf16x8*)&Bs[R * 32 + ((ks ^ ((R >> 1) & 3)) << 3)];
        }
#pragma unroll
        for (int i = 0; i < 2; i++)
#pragma unroll
            for (int j = 0; j < 4; j++)
                acc[i][j] = __builtin_amdgcn_mfma_f32_16x16x32_bf16(af[i], bvf[j], acc[i][j], 0, 0, 0);
        __syncthreads();
    }
    // ---- fused epilogue: band dots, atomic global reduce ----
    int colg[4]; float ub[4], vb[4];
#pragma unroll
    for (int j = 0; j < 4; j++) {
        colg[j] = n0 + wc * 64 + j * 16 + (lane & 15);
        ub[j] = u[colg[j]];
        vb[j] = v[colg[j]];
    }
#pragma unroll
    for (int i = 0; i < 2; i++) {
#pragma unroll
        for (int rr = 0; rr < 4; rr++) {
            const int row = m0 + wr * 32 + i * 16 + (lane >> 4) * 4 + rr;
            const int rm = (row == 0) ? 0 : row - 1;
            const int rp = (row == MM - 1) ? MM - 1 : row + 1;
            const __bf16* hm = A + (size_t)rm * DD;
            const __bf16* hz = A + (size_t)row * DD;
            const __bf16* hp = A + (size_t)rp * DD;
            float dua = 0.f, dna = 0.f, wa = 0.f;
#pragma unroll
            for (int j = 0; j < 4; j++) {
                const float Rv = acc[i][j][rr] + ub[j];
                dua += Rv * (float)hm[colg[j]];
                dna += Rv * (float)hp[colg[j]];
                wa  += vb[j] * (float)hz[colg[j]];
            }
#pragma unroll
            for (int o = 1; o < 16; o <<= 1) {
                dua += __shfl_xor(dua, o);
                dna += __shfl_xor(dna, o);
                wa  += __shfl_xor(wa, o);
            }
            if ((lane & 15) == 0) {
                atomicAdd(&du_g[row], dua);
                atomicAdd(&dn_g[row], dna);
                atomicAdd(&w_g[row], wa);
            }
        }
    }
}

// ============ K2: per-batch softmax, nb, log2, double prefix scan ============
__global__ __launch_bounds__(256) void scan_kernel(const float* __restrict__ du_g,
        const float* __restrict__ dn_g, const float* __restrict__ w_g,
        const float* __restrict__ cbp, const int* __restrict__ fl_i,
        const float* __restrict__ prsup,
        float* __restrict__ nb, double* __restrict__ P2) {
    const int b = blockIdx.x;
    const int t = threadIdx.x;
    __shared__ float du_s[SS], dn_s[SS], w_s[SS], sh_pd[SS];
    __shared__ double warr[256];
    for (int x = t; x < SS; x += 256) {
        du_s[x] = du_g[b * SS + x];
        dn_s[x] = dn_g[b * SS + x];
        w_s[x]  = w_g[b * SS + x];
    }
    __syncthreads();
    const float cb = cbp[0];
    float pu_r[8];
#pragma unroll
    for (int e = 0; e < 8; e++) {
        const int s = t * 8 + e;
        const int fl = fl_i[b * SS + s];
        const bool au = fl & 1, ad = fl & 2;
        float puv = 0.f, pdv = 0.f;
        if (au || ad) {
            const float eu = au ? (du_s[s + 1] + w_s[s + 1] + cb) * (1.0f / DD) : 0.f;
            const float ed = ad ? (dn_s[s - 1] + w_s[s - 1] + cb) * (1.0f / DD) : 0.f;
            float mx = au ? eu : ed;
            if (au && ad) mx = fmaxf(eu, ed);
            const float zu = au ? expf(eu - mx) : 0.f;
            const float zd = ad ? expf(ed - mx) : 0.f;
            const float iz = 1.f / (zu + zd);
            puv = zu * iz; pdv = zd * iz;
        }
        pu_r[e] = puv;
        sh_pd[s] = pdv;
    }
    __syncthreads();
    double L[8];
    double mysum = 0.0;
#pragma unroll
    for (int e = 0; e < 8; e++) {
        const int s = t * 8 + e;
        double Lv = 0.0;
        float nbv = 0.f;
        if (s < SS - 1) {
            nbv = sqrtf(pu_r[e] * sh_pd[s + 1] + 1e-9f);
            const float pr = prsup[b * SS + s];
            const float nsup = pr + (1.f - pr) * nbv;
            Lv = (double)log2f(nsup + 1e-9f);
        }
        nb[b * SS + s] = nbv;
        L[e] = Lv; mysum += Lv;
    }
    warr[t] = mysum;
    __syncthreads();
    for (int o = 1; o < 256; o <<= 1) {
        double vv = 0.0;
        if (t >= o) vv = warr[t - o];
        __syncthreads();
        if (t >= o) warr[t] += vv;
        __syncthreads();
    }
    double run = warr[t] - mysum;    // exclusive prefix across threads
#pragma unroll
    for (int e = 0; e < 8; e++) {
        P2[(size_t)b * SS + t * 8 + e] = run;
        run += L[e];
    }
}

// ============ K3: fused elementwise output (g and n), 8 elems/thread ============
__global__ __launch_bounds__(256) void out_kernel(const float* __restrict__ prior,
        const float* __restrict__ nb, const double* __restrict__ P2,
        float* __restrict__ gout, float* __restrict__ nout) {
    const size_t t8 = (size_t)blockIdx.x * 256 + threadIdx.x;
    const int b = (int)(t8 >> 19);                 // (t8*8) / (SS*SS)
    const size_t off = t8 << 3;                    // element base
    const size_t r = off & ((1u << 22) - 1);
    const int i  = (int)(r >> 11);                 // row
    const int k0 = (int)(r & 2047);                // col base
    const f32x4 p0 = *(const f32x4*)(prior + off);
    const f32x4 p1 = *(const f32x4*)(prior + off + 4);
    const double* Pb = P2 + ((size_t)b << 11);
    const double Pi = Pb[i];
    const float* nbb = nb + ((size_t)b << 11);
    f32x4 g0, g1, n0, n1;
#pragma unroll
    for (int c = 0; c < 8; c++) {
        const int k = k0 + c;
        const float pr = (c < 4) ? p0[c] : p1[c - 4];
        float vv = 3.16227766016838e-5f;           // sqrt(1e-9)
        if (k == i + 1)      vv = nbb[i];
        else if (k == i - 1) vv = nbb[k];
        const float nval = pr + (1.f - pr) * vv;
        float g;
        if (k == i) {
            g = nval;
        } else {
            const double Pk = Pb[k];
            const double dd = (k > i) ? (Pk - Pi) : (Pi - Pk);
            g = exp2f((float)dd) + 1e-9f;
        }
        if (c < 4) { g0[c] = g; n0[c] = nval; }
        else       { g1[c - 4] = g; n1[c - 4] = nval; }
    }
    *(f32x4*)(gout + off)     = g0;
    *(f32x4*)(gout + off + 4) = g1;
    *(f32x4*)(nout + off)     = n0;
    *(f32x4*)(nout + off + 4) = n1;
}

extern "C" void kernel_launch(void* const* d_in, const int* in_sizes, int n_in,
                              void* d_out, int out_size, void* d_ws, size_t ws_size,
                              hipStream_t stream) {
    const float* hs    = (const float*)d_in[0];
    const int*   att   = (const int*)d_in[1];
    const float* prior = (const float*)d_in[2];
    const float* ln_w  = (const float*)d_in[3];
    const float* ln_b  = (const float*)d_in[4];
    const float* wq    = (const float*)d_in[5];
    const float* bq    = (const float*)d_in[6];
    const float* wk    = (const float*)d_in[7];
    const float* bk    = (const float*)d_in[8];

    float* gout = (float*)d_out;                       // g first (return order)
    float* nout = gout + (size_t)BB * SS * SS;

    char* ws = (char*)d_ws;
    __bf16* h     = (__bf16*)(ws);                     // 12,582,912
    __bf16* G     = (__bf16*)(ws + 12582912);          //  1,179,648
    float*  u     = (float*) (ws + 13762560);          //      3,072
    float*  v     = (float*) (ws + 13765632);          //      3,072
    float*  cbp   = (float*) (ws + 13768704);          //        256
    int*    fl    = (int*)   (ws + 13768960);          //     32,768
    float*  prsup = (float*) (ws + 13801728);          //     32,768
    float*  du_g  = (float*) (ws + 13834496);          //     32,768
    float*  dn_g  = (float*) (ws + 13867264);          //     32,768
    float*  w_g   = (float*) (ws + 13900032);          //     32,768
    float*  nbuf  = (float*) (ws + 13932800);          //     32,768
    double* P2    = (double*)(ws + 13965568);          //     65,536

    combined_kernel<<<dim3(2609), dim3(256), 0, stream>>>(hs, ln_w, ln_b, wq, wk, bq, bk,
                                                          att, prior, G, u, v, cbp, h, fl, prsup,
                                                          du_g, dn_g, w_g);
    rgemm_kernel<<<dim3(768), dim3(256), 0, stream>>>(h, G, u, v, du_g, dn_g, w_g);
    scan_kernel<<<dim3(BB), dim3(256), 0, stream>>>(du_g, dn_g, w_g, cbp, fl, prsup, nbuf, P2);
    out_kernel<<<dim3((BB * SS * SS / 8) / 256), dim3(256), 0, stream>>>(prior, nbuf, P2, gout, nout);
}